// Round 11
// baseline (2682.703 us; speedup 1.0000x reference)
//
#include <hip/hip_runtime.h>
#include <stdint.h>
#include <math.h>

#define N_ROWS 131072
#define K_CEN  2048
#define D_DIM  1024
#define BM     64
#define CSCALE 16.0f      // centroid pre-scale: lifts c out of e4m3 subnormal range
#define TAUS   6.5f       // scaled units = 0.41 cosine; ~5.6 sigma of pairwise fp8 noise
#define CAND_CAP 32

typedef float f32x4  __attribute__((ext_vector_type(4)));
typedef int   i32x4  __attribute__((ext_vector_type(4)));

__device__ __forceinline__ unsigned f2ord(float f) {
  unsigned u = __float_as_uint(f);
  return (u & 0x80000000u) ? ~u : (u | 0x80000000u);  // monotone float->uint
}
__device__ __forceinline__ float ord2f(unsigned o) {
  unsigned u = (o & 0x80000000u) ? (o & 0x7fffffffu) : ~o;
  return __uint_as_float(u);
}
__device__ __forceinline__ unsigned pk4_fp8(float a0, float a1, float a2, float a3) {
  unsigned w = 0;
  w = __builtin_amdgcn_cvt_pk_fp8_f32(a0, a1, w, false);   // bytes 0,1
  w = __builtin_amdgcn_cvt_pk_fp8_f32(a2, a3, w, true);    // bytes 2,3
  return w;
}

// ---- prep: centroids fp32 -> fp8 e4m3 x CSCALE (row-major [K][D]) into ws (2 MB) ----
__global__ __launch_bounds__(256) void cvt_centroids(const float* __restrict__ cen,
                                                     unsigned* __restrict__ outb) {
  int i = blockIdx.x * 256 + threadIdx.x;           // 524288 threads x 4 floats -> 4 bytes
  float4 v = reinterpret_cast<const float4*>(cen)[i];
  outb[i] = pk4_fp8(v.x * CSCALE, v.y * CSCALE, v.z * CSCALE, v.w * CSCALE);
}

// ---- main: A resident in LDS as fp8 (64 KB -> 2 WGs/CU, 4 waves/SIMD); B fp8 streamed
// L2->regs depth-3 (fits 128-VGPR cap: acc64+breg24+areg16+addr~20). cenb = 2 MB,
// L2-resident. Barrier-free K loop, sched_barrier-pinned phases. Exact fp64 rescore;
// candidate-list overflow falls back to a full exact rescan (never drops the argmax).
// Wave w owns cols [w*256, w*256+256), tile 64x64, acc 4x4 of 16x16, K=32/MFMA.
__global__ __launch_bounds__(512, 1) void assign_rows(
    const float* __restrict__ vec, const float* __restrict__ cenf,
    const unsigned char* __restrict__ cenb, int* __restrict__ out)
{
  __shared__ unsigned char v_lds[BM * D_DIM];       // 64 KB fp8, XOR-swizzled
  __shared__ unsigned rowmax_ord[BM];
  __shared__ int cand_cnt[BM];
  __shared__ unsigned candv[BM][CAND_CAP];          // fp8-dot score (ordered uint, scaled)
  __shared__ unsigned short candc[BM][CAND_CAP];    // centroid index

  const int tid  = threadIdx.x;
  const int lane = tid & 63;
  const int wid  = tid >> 6;     // 8 waves, each owns a 256-col strip
  const long row0 = (long)blockIdx.x * BM;

  if (tid < BM) { rowmax_ord[tid] = f2ord(-3.0e38f); cand_cnt[tid] = 0; }

  // stage v rows -> swizzled fp8 LDS (64 rows x 1024); nt loads (protect cenb in L2)
  #pragma unroll
  for (int it = 0; it < 8; ++it) {
    int cid = it * 512 + tid;          // 4096 chunks of 16 elems
    int r  = cid >> 6;                 // 64 chunks of 16 per row
    int dc = (cid & 63) << 4;
    const f32x4* vp = reinterpret_cast<const f32x4*>(vec + (row0 + r) * D_DIM + dc);
    f32x4 a = __builtin_nontemporal_load(vp);
    f32x4 b = __builtin_nontemporal_load(vp + 1);
    f32x4 c = __builtin_nontemporal_load(vp + 2);
    f32x4 d = __builtin_nontemporal_load(vp + 3);
    i32x4 pk;
    pk[0] = (int)pk4_fp8(a[0], a[1], a[2], a[3]);
    pk[1] = (int)pk4_fp8(b[0], b[1], b[2], b[3]);
    pk[2] = (int)pk4_fp8(c[0], c[1], c[2], c[3]);
    pk[3] = (int)pk4_fp8(d[0], d[1], d[2], d[3]);
    int byt = (r << 10) + dc;          // row stride 1024 B
    *reinterpret_cast<i32x4*>(reinterpret_cast<char*>(v_lds) + (byt ^ ((r & 7) << 4))) = pk;
  }
  __syncthreads();

  const int l15 = lane & 15;
  const int lq  = lane >> 4;
  const int amask = (l15 & 7) << 4;                 // lane-constant XOR swizzle (16B blocks)
  const int abase = (l15 << 10) + (lq << 3);        // row*1024B + k-octet*8B
  const char* v_bytes = reinterpret_cast<const char*>(v_lds);
  const char* c_bytes = reinterpret_cast<const char*>(cenb);

  for (int cb = 0; cb < 4; ++cb) {
    const int colbase = (wid << 8) + (cb << 6);
    const size_t bbase = ((size_t)(colbase + l15) << 10) + (size_t)(lq << 3);
    const char* bp0 = c_bytes + bbase;              // per-ni bases, 16 cols = 16 KB apart
    const char* bp1 = bp0 + 16384;
    const char* bp2 = bp1 + 16384;
    const char* bp3 = bp2 + 16384;

    f32x4 acc[4][4];
    #pragma unroll
    for (int mi = 0; mi < 4; ++mi)
      #pragma unroll
      for (int ni = 0; ni < 4; ++ni) acc[mi][ni] = (f32x4){0.f,0.f,0.f,0.f};

    long breg[3][4];   // [k%3][ni] : depth-3 L2 prefetch (24 VGPR)
    long areg[2][4];   // [k&1][mi] : depth-2 LDS prefetch (16 VGPR)

    // prologue: B(k=0..2), A(k=0); fence pins these before the loop
    #pragma unroll
    for (int k = 0; k < 3; ++k) {
      breg[k][0] = *reinterpret_cast<const long*>(bp0 + (k << 5));
      breg[k][1] = *reinterpret_cast<const long*>(bp1 + (k << 5));
      breg[k][2] = *reinterpret_cast<const long*>(bp2 + (k << 5));
      breg[k][3] = *reinterpret_cast<const long*>(bp3 + (k << 5));
    }
    {
      int ta = abase ^ amask;
      #pragma unroll
      for (int mi = 0; mi < 4; ++mi)
        areg[0][mi] = *reinterpret_cast<const long*>(v_bytes + ta + (mi << 14));
    }
    __builtin_amdgcn_sched_barrier(0);

    #pragma unroll
    for (int kc = 0; kc < 32; ++kc) {
      // phase 1: A(kc+1) from LDS (depth-1 ahead), ds_read_b64, ~conflict-free
      if (kc + 1 < 32) {
        int ta = (abase + ((kc + 1) << 5)) ^ amask;
        #pragma unroll
        for (int mi = 0; mi < 4; ++mi)
          areg[(kc + 1) & 1][mi] = *reinterpret_cast<const long*>(v_bytes + ta + (mi << 14));
      }
      __builtin_amdgcn_sched_barrier(0);
      // phase 2: 16 MFMA on A(kc),B(kc); B(kc+3) re-issued per-ni after its WAR clears.
      // Counted vmcnt (two younger iterations outstanding), never 0.
      __builtin_amdgcn_s_setprio(1);
      #pragma unroll
      for (int ni = 0; ni < 4; ++ni) {
        #pragma unroll
        for (int mi = 0; mi < 4; ++mi)
          acc[mi][ni] = __builtin_amdgcn_mfma_f32_16x16x32_fp8_fp8(
              areg[kc & 1][mi], breg[kc % 3][ni], acc[mi][ni], 0, 0, 0);
        if (kc + 3 < 32) {
          const int ko = (kc + 3) << 5;
          const char* bp = ni==0?bp0: ni==1?bp1: ni==2?bp2: bp3;
          breg[kc % 3][ni] = *reinterpret_cast<const long*>(bp + ko);
        }
      }
      __builtin_amdgcn_s_setprio(0);
      __builtin_amdgcn_sched_barrier(0);
    }

    // running row-max (C layout: col = l15, row = mi*16 + lq*4 + j) — scaled units
    #pragma unroll
    for (int mi = 0; mi < 4; ++mi) {
      #pragma unroll
      for (int j = 0; j < 4; ++j) {
        float mv = fmaxf(fmaxf(acc[mi][0][j], acc[mi][1][j]),
                         fmaxf(acc[mi][2][j], acc[mi][3][j]));
        mv = fmaxf(mv, __shfl_xor(mv, 1));
        mv = fmaxf(mv, __shfl_xor(mv, 2));
        mv = fmaxf(mv, __shfl_xor(mv, 4));
        mv = fmaxf(mv, __shfl_xor(mv, 8));
        if (l15 == 0) {
          int row = (mi << 4) + (lq << 2) + j;
          atomicMax(&rowmax_ord[row], f2ord(mv));
        }
      }
    }
    // include ALL waves' maxima for this superblock before appending -> ~4x fewer
    // appends than the racy version (threshold is much tighter). Conservative still:
    // running max <= final max, so no true candidate is ever missed.
    __syncthreads();
    #pragma unroll
    for (int mi = 0; mi < 4; ++mi) {
      #pragma unroll
      for (int j = 0; j < 4; ++j) {
        int row = (mi << 4) + (lq << 2) + j;
        float thr = ord2f(rowmax_ord[row]) - TAUS;
        #pragma unroll
        for (int ni = 0; ni < 4; ++ni) {
          float v = acc[mi][ni][j];
          if (v >= thr) {
            int slot = atomicAdd(&cand_cnt[row], 1);
            if (slot < CAND_CAP) {
              candv[row][slot] = f2ord(v);
              candc[row][slot] = (unsigned short)(colbase + (ni << 4) + l15);
            }
          }
        }
      }
    }
  }
  __syncthreads();

  // epilogue per row: overflow => exact full rescan; else single fp8-survivor =>
  // answer directly; else exact fp64 rescore of survivors. First-occurrence tie-break.
  for (int r = wid; r < BM; r += 8) {
    const long grow = row0 + r;
    const int raw = cand_cnt[r];
    const float* vrow = vec + grow * D_DIM + (lane << 4);

    if (raw <= CAND_CAP) {
      const unsigned thro = f2ord(ord2f(rowmax_ord[r]) - TAUS);
      bool sv = (lane < raw) && (candv[r][lane] >= thro);
      unsigned long long bal = __ballot(sv);
      int nsurv = __popcll(bal);
      if (nsurv == 1) {
        int idx = __builtin_ctzll(bal);
        if (lane == 0) out[grow] = (int)candc[r][idx];
        continue;
      }
      float va[16];
      #pragma unroll
      for (int i = 0; i < 16; ++i) va[i] = vrow[i];
      double bestv = -1.0e300;
      int    besti = 0x7fffffff;
      for (int ci = 0; ci < raw; ++ci) {
        if (candv[r][ci] < thro) continue;
        const int col = (int)candc[r][ci];
        const float* crow = cenf + ((size_t)col << 10) + (lane << 4);
        double s = 0.0;
        #pragma unroll
        for (int i = 0; i < 16; ++i) s = fma((double)va[i], (double)crow[i], s);
        s += __shfl_xor(s, 32);
        s += __shfl_xor(s, 16);
        s += __shfl_xor(s, 8);
        s += __shfl_xor(s, 4);
        s += __shfl_xor(s, 2);
        s += __shfl_xor(s, 1);
        if (s > bestv || (s == bestv && col < besti)) { bestv = s; besti = col; }
      }
      if (lane == 0) out[grow] = besti;
    } else {
      // candidate list overflowed (P ~ 1e-11/row): exact rescan of all K centroids
      float va[16];
      #pragma unroll
      for (int i = 0; i < 16; ++i) va[i] = vrow[i];
      double bestv = -1.0e300;
      int    besti = 0x7fffffff;
      for (int col = 0; col < K_CEN; ++col) {
        const float* crow = cenf + ((size_t)col << 10) + (lane << 4);
        double s = 0.0;
        #pragma unroll
        for (int i = 0; i < 16; ++i) s = fma((double)va[i], (double)crow[i], s);
        s += __shfl_xor(s, 32);
        s += __shfl_xor(s, 16);
        s += __shfl_xor(s, 8);
        s += __shfl_xor(s, 4);
        s += __shfl_xor(s, 2);
        s += __shfl_xor(s, 1);
        if (s > bestv) { bestv = s; besti = col; }
      }
      if (lane == 0) out[grow] = besti;
    }
  }
}

extern "C" void kernel_launch(void* const* d_in, const int* in_sizes, int n_in,
                              void* d_out, int out_size, void* d_ws, size_t ws_size,
                              hipStream_t stream) {
  const float* vec  = (const float*)d_in[0];   // [131072][1024] fp32
  const float* cenf = (const float*)d_in[1];   // [2048][1024] fp32 (pre-normalized)
  unsigned* cenb = (unsigned*)d_ws;            // 2 MB fp8 e4m3 centroids (x16 scaled)
  int* out = (int*)d_out;                      // [131072] int32 assignments

  cvt_centroids<<<(K_CEN * D_DIM / 4) / 256, 256, 0, stream>>>(cenf, cenb);
  assign_rows<<<N_ROWS / BM, 512, 0, stream>>>(vec, cenf,
                                               (const unsigned char*)cenb, out);
}